// Round 7
// baseline (633.994 us; speedup 1.0000x reference)
//
#include <hip/hip_runtime.h>
#include <cstdint>
#include <cstddef>

// Problem constants
#define NB 8
#define TT 2048
#define DD 512
#define FF 2048
#define NE 16
#define NT (NB*TT)              // 16384 tokens
#define NPOS (NT*2)             // 32768 dispatch slots (K=2)
#define MT256 (NPOS/256 + NE)   // 144 max 256-row M-tiles (per-expert ceil to 256)
#define NPAL (MT256*256)        // 36864 padded positions
#define MT128 (NPAL/128)        // 288 max 128-row M-tiles

typedef short v8s __attribute__((ext_vector_type(8)));   // 8 x bf16 bits (4 VGPRs)
typedef float v4f __attribute__((ext_vector_type(4)));

__device__ __forceinline__ uint16_t f2bf(float v) {
  union { float f; uint32_t u; } c; c.f = v;
  uint32_t r = (c.u + 0x7FFFu + ((c.u >> 16) & 1u)) >> 16;   // RNE
  return (uint16_t)r;
}
__device__ __forceinline__ float bf2f(uint16_t b) {
  union { uint32_t u; float f; } c; c.u = ((uint32_t)b) << 16;
  return c.f;
}
__device__ __forceinline__ float gelu_t(float x) {  // jax.nn.gelu approximate=True
  float u = 0.7978845608028654f * (x + 0.044715f * x * x * x);
  return 0.5f * x * (1.0f + tanhf(u));
}
__device__ __forceinline__ void gl_lds16(const void* g, void* l) {
  __builtin_amdgcn_global_load_lds(
      (const __attribute__((address_space(1))) uint32_t*)g,
      (__attribute__((address_space(3))) uint32_t*)l, 16, 0, 0);
}

// ---------------- zero small scratch ----------------
__global__ void k_zero(int* p, int n) {
  for (int i = threadIdx.x; i < n; i += 256) p[i] = 0;
}

// ---------------- transpose + convert weights: dst[e][c][r] = src[e][r][c] ----------------
__global__ __launch_bounds__(256) void k_trans(const float* __restrict__ src,
                                               uint16_t* __restrict__ dst,
                                               int rows, int cols) {
  __shared__ float t[32][33];
  const size_t eo = (size_t)blockIdx.z * rows * cols;
  const float* s = src + eo;
  uint16_t* d = dst + eo;
  int c0 = blockIdx.x * 32, r0 = blockIdx.y * 32;
  int tx = threadIdx.x, ty = threadIdx.y;
#pragma unroll
  for (int i = 0; i < 4; ++i)
    t[ty + i * 8][tx] = s[(size_t)(r0 + ty + i * 8) * cols + c0 + tx];
  __syncthreads();
#pragma unroll
  for (int i = 0; i < 4; ++i)
    d[(size_t)(c0 + ty + i * 8) * rows + r0 + tx] = f2bf(t[tx][ty + i * 8]);
}

// ---------------- router (fp64 logits for exact top-k agreement) + x->bf16 ----------------
__global__ __launch_bounds__(256) void k_router(
    const float* __restrict__ x, const float* __restrict__ Wr,
    uint16_t* __restrict__ xb,
    int* __restrict__ topi, float* __restrict__ gates,
    int* __restrict__ cnt_part, int* __restrict__ f_part, float* __restrict__ P_part) {
  __shared__ int s_cnt[NE]; __shared__ int s_f[NE]; __shared__ float s_P[NE];
  const int tid = threadIdx.x;
  if (tid < NE) { s_cnt[tid] = 0; s_f[tid] = 0; s_P[tid] = 0.f; }
  __syncthreads();
  const int wid = tid >> 6, lane = tid & 63;
  const int t = blockIdx.x * 4 + wid;
  const float* xr = x + (size_t)t * DD + lane * 8;
  double pe[NE];
#pragma unroll
  for (int e = 0; e < NE; ++e) pe[e] = 0.0;
  float xv8[8];
#pragma unroll
  for (int j = 0; j < 8; ++j) xv8[j] = xr[j];
#pragma unroll
  for (int j = 0; j < 8; ++j) {
    const double xv = (double)xv8[j];
    const float* wr = Wr + (size_t)(lane * 8 + j) * NE;
#pragma unroll
    for (int e = 0; e < NE; ++e) pe[e] += xv * (double)wr[e];
  }
  // write bf16 copy of x (fused former k_cvt_x)
  {
    ushort4 o0, o1;
    o0.x = f2bf(xv8[0]); o0.y = f2bf(xv8[1]); o0.z = f2bf(xv8[2]); o0.w = f2bf(xv8[3]);
    o1.x = f2bf(xv8[4]); o1.y = f2bf(xv8[5]); o1.z = f2bf(xv8[6]); o1.w = f2bf(xv8[7]);
    uint16_t* xo = xb + (size_t)t * DD + lane * 8;
    *(ushort4*)xo = o0; *(ushort4*)(xo + 4) = o1;
  }
#pragma unroll
  for (int m = 1; m < 64; m <<= 1) {
#pragma unroll
    for (int e = 0; e < NE; ++e) pe[e] += __shfl_xor(pe[e], m, 64);
  }
  if (lane == 0) {
    double mx = pe[0];
#pragma unroll
    for (int e = 1; e < NE; ++e) mx = fmax(mx, pe[e]);
    double s = 0.0, pr[NE];
#pragma unroll
    for (int e = 0; e < NE; ++e) { pr[e] = exp(pe[e] - mx); s += pr[e]; }
    const double inv = 1.0 / s;
    int i0 = 0; double v0 = pe[0];
#pragma unroll
    for (int e = 1; e < NE; ++e) if (pe[e] > v0) { v0 = pe[e]; i0 = e; }
    int i1 = -1; double v1 = -1.0e300;
#pragma unroll
    for (int e = 0; e < NE; ++e) if (e != i0 && pe[e] > v1) { v1 = pe[e]; i1 = e; }
    const double g0 = 1.0 / (1.0 + exp(v1 - v0));
    topi[t * 2] = i0; topi[t * 2 + 1] = i1;
    gates[t * 2] = (float)g0; gates[t * 2 + 1] = (float)(1.0 - g0);
    atomicAdd(&s_cnt[i0], 1); atomicAdd(&s_cnt[i1], 1);
    atomicAdd(&s_f[i0], 1);
#pragma unroll
    for (int e = 0; e < NE; ++e) atomicAdd(&s_P[e], (float)(pr[e] * inv));
  }
  __syncthreads();
  if (tid < NE) {
    const int slot = (blockIdx.x & 63) * NE + tid;
    if (s_cnt[tid]) atomicAdd(&cnt_part[slot], s_cnt[tid]);
    if (s_f[tid]) atomicAdd(&f_part[slot], s_f[tid]);
    atomicAdd(&P_part[slot], s_P[tid]);
  }
}

// ---------------- reduce partials -> counts, 256-aligned offsets, aux loss, pad fill ----------------
__global__ __launch_bounds__(256) void k_reduce(
    const int* __restrict__ cnt_part, const int* __restrict__ f_part,
    const float* __restrict__ P_part, int* __restrict__ counts,
    int* __restrict__ goff, int* __restrict__ cursor,
    int* __restrict__ tokofp, float* __restrict__ aux_out) {
  __shared__ int sc[NE]; __shared__ int sgo[NE + 1]; __shared__ double sterm[NE];
  const int tid = threadIdx.x;
  if (tid < NE) {
    int c = 0, f = 0; float P = 0.f;
    for (int s = 0; s < 64; ++s) {
      c += cnt_part[s * NE + tid]; f += f_part[s * NE + tid]; P += P_part[s * NE + tid];
    }
    counts[tid] = c; sc[tid] = c;
    sterm[tid] = ((double)f / NT) * ((double)P / NT);
  }
  __syncthreads();
  if (tid == 0) {
    double a = 0;
    for (int e = 0; e < NE; ++e) a += sterm[e];
    *aux_out = (float)(NE * a);
    int o = 0; sgo[0] = 0;
    for (int e = 0; e < NE; ++e) { o += ((sc[e] + 255) >> 8) << 8; sgo[e + 1] = o; }
    for (int e = 0; e <= NE; ++e) goff[e] = sgo[e];
    for (int e = 0; e < NE; ++e) cursor[e] = sgo[e];
  }
  __syncthreads();
  for (int e = 0; e < NE; ++e) {
    const int st = sgo[e] + sc[e], en = sgo[e + 1];
    for (int i = st + tid; i < en; i += 256) tokofp[i] = 0;  // padded rows gather token 0
  }
}

// ---------------- build per-expert token lists ----------------
__global__ __launch_bounds__(256) void k_build(const int* __restrict__ topi,
                                               int* __restrict__ cursor,
                                               int* __restrict__ tokofp,
                                               int* __restrict__ pos) {
  __shared__ int scnt[NE]; __shared__ int sbase[NE];
  const int tid = threadIdx.x;
  const int t = blockIdx.x * 256 + tid;
  if (tid < NE) scnt[tid] = 0;
  __syncthreads();
  const int e0 = topi[t * 2], e1 = topi[t * 2 + 1];
  const int r0 = atomicAdd(&scnt[e0], 1);
  const int r1 = atomicAdd(&scnt[e1], 1);
  __syncthreads();
  if (tid < NE) sbase[tid] = scnt[tid] ? atomicAdd(&cursor[tid], scnt[tid]) : 0;
  __syncthreads();
  const int p0 = sbase[e0] + r0, p1 = sbase[e1] + r1;
  tokofp[p0] = t; tokofp[p1] = t;
  pos[t * 2] = p0; pos[t * 2 + 1] = p1;
}

// ---------------- BMxBNx64 bf16 MFMA GEMM, double-buffered 2-phase pipeline ----------------
// GATHER_GELU=true : A = xb gathered via tokofp (K=512),  epilogue gelu -> h
// GATHER_GELU=false: A = h rows direct (K=2048),          epilogue bias -> ybuf
// LDS rows are 64 bf16 (128 B); 16-B slots XOR-swizzled by (row&7) on BOTH the
// pre-swizzled global source and the ds_read address (linear gl_lds dest).
template <int BM, int BN, int NTHR, int KDIM, int NDIM, bool GATHER_GELU>
__global__ __launch_bounds__(NTHR, 2) void k_gemm(
    const uint16_t* __restrict__ Abase, const uint16_t* __restrict__ Bt,
    const float* __restrict__ bias, uint16_t* __restrict__ Cout,
    const int* __restrict__ goff, const int* __restrict__ tokofp) {
  constexpr int WAVES = NTHR / 64;
  constexpr int WN = (WAVES == 8) ? 4 : 2;
  constexpr int WM = WAVES / WN;
  constexpr int MF = BM / (WM * 16);        // m-fragments per wave
  constexpr int NF = BN / (WN * 16);        // n-fragments per wave
  constexpr int LA = BM * 64 / (NTHR * 8);  // gl_lds16 per thread for A per K-tile
  constexpr int LB = BN * 64 / (NTHR * 8);
  constexpr int NKT = KDIM / 64;
  __shared__ __align__(16) uint16_t As[2 * BM * 64];
  __shared__ __align__(16) uint16_t Bs[2 * BN * 64];

  const int ntiles = goff[NE] / BM;
  const int gy = blockIdx.y;
  if (gy >= ntiles) return;
  int e = 0;
#pragma unroll
  for (int i = 1; i < NE; ++i) if (gy * BM >= goff[i]) e = i;
  const int row0 = gy * BM;
  const int n0 = blockIdx.x * BN;
  const int tid = threadIdx.x, lane = tid & 63;
  const int wid = tid >> 6;
  const int wm = wid / WN, wn = wid % WN;

  // ---- staging pointers (linear LDS dest, pre-swizzled global source) ----
  const uint16_t* Be = Bt + (size_t)e * ((size_t)NDIM * KDIM);
  const uint16_t* ag[LA]; const uint16_t* bg[LB];
  int ldsOffA[LA], ldsOffB[LB];
#pragma unroll
  for (int r = 0; r < LA; ++r) {
    const int flat = r * NTHR + tid;
    const int row = flat >> 3, slot = flat & 7;
    ldsOffA[r] = flat * 8;
    size_t srow;
    if (GATHER_GELU) srow = (size_t)tokofp[row0 + row];
    else             srow = (size_t)(row0 + row);
    ag[r] = Abase + srow * KDIM + (slot ^ (row & 7)) * 8;
  }
#pragma unroll
  for (int r = 0; r < LB; ++r) {
    const int flat = r * NTHR + tid;
    const int row = flat >> 3, slot = flat & 7;
    ldsOffB[r] = flat * 8;
    bg[r] = Be + (size_t)(n0 + row) * KDIM + (slot ^ (row & 7)) * 8;
  }

  // ---- fragment read offsets: XOR term is uniformly (lane&7)<<4 ----
  const int kswz[2] = {
      (((lane >> 4) << 4)) ^ ((lane & 7) << 4),
      (64 + ((lane >> 4) << 4)) ^ ((lane & 7) << 4)};
  const int aRow = (wm * (MF * 16) + (lane & 15)) * 128;  // byte offset of frag row
  const int bRow = (wn * (NF * 16) + (lane & 15)) * 128;

  v4f acc[MF][NF];
#pragma unroll
  for (int i = 0; i < MF; ++i)
#pragma unroll
    for (int j = 0; j < NF; ++j) acc[i][j] = (v4f){0.f, 0.f, 0.f, 0.f};

  // ---- prologue: stage K-tile 0 into buffer 0 ----
#pragma unroll
  for (int r = 0; r < LA; ++r) gl_lds16(ag[r], As + ldsOffA[r]);
#pragma unroll
  for (int r = 0; r < LB; ++r) gl_lds16(bg[r], Bs + ldsOffB[r]);
  __syncthreads();   // compiler emits vmcnt(0) drain before barrier

  int cur = 0;
  for (int kt = 0; kt < NKT; ++kt) {
    // issue next K-tile's loads into the other buffer BEFORE compute
    if (kt + 1 < NKT) {
      uint16_t* an = As + (cur ^ 1) * (BM * 64);
      uint16_t* bn = Bs + (cur ^ 1) * (BN * 64);
#pragma unroll
      for (int r = 0; r < LA; ++r) gl_lds16(ag[r] + (kt + 1) * 64, an + ldsOffA[r]);
#pragma unroll
      for (int r = 0; r < LB; ++r) gl_lds16(bg[r] + (kt + 1) * 64, bn + ldsOffB[r]);
    }
    const char* ab = (const char*)(As + cur * (BM * 64));
    const char* bb = (const char*)(Bs + cur * (BN * 64));
#pragma unroll
    for (int kk = 0; kk < 2; ++kk) {
      v8s af[MF], bf[NF];
#pragma unroll
      for (int f = 0; f < MF; ++f)
        af[f] = *(const v8s*)(ab + aRow + f * 2048 + kswz[kk]);
#pragma unroll
      for (int f = 0; f < NF; ++f)
        bf[f] = *(const v8s*)(bb + bRow + f * 2048 + kswz[kk]);
#pragma unroll
      for (int m = 0; m < MF; ++m)
#pragma unroll
        for (int n = 0; n < NF; ++n)
          acc[m][n] = __builtin_amdgcn_mfma_f32_16x16x32_bf16(af[m], bf[n], acc[m][n], 0, 0, 0);
    }
    __syncthreads();   // drains next-tile vmcnt + swaps buffer roles
    cur ^= 1;
  }

  // ---- epilogue: C layout col=lane&15, row=(lane>>4)*4+j ----
#pragma unroll
  for (int fn = 0; fn < NF; ++fn) {
    const int col = n0 + wn * (NF * 16) + fn * 16 + (lane & 15);
    const float bv = bias[e * NDIM + col];
#pragma unroll
    for (int fm = 0; fm < MF; ++fm) {
      const int rb = row0 + wm * (MF * 16) + fm * 16 + ((lane >> 4) << 2);
#pragma unroll
      for (int j = 0; j < 4; ++j) {
        float v = acc[fm][fn][j] + bv;
        if (GATHER_GELU) v = gelu_t(v);
        Cout[(size_t)(rb + j) * NDIM + col] = f2bf(v);
      }
    }
  }
}

// ---------------- combine: out[t] = g0*y[pos0] + g1*y[pos1] ----------------
__global__ __launch_bounds__(256) void k_comb(const uint16_t* __restrict__ ybuf,
                                              const int* __restrict__ pos,
                                              const float* __restrict__ gates,
                                              float* __restrict__ out) {
  const int t = blockIdx.x;
  const int d = threadIdx.x * 2;
  const float g0 = gates[t * 2], g1 = gates[t * 2 + 1];
  const uint32_t u0 = *(const uint32_t*)(ybuf + (size_t)pos[t * 2] * DD + d);
  const uint32_t u1 = *(const uint32_t*)(ybuf + (size_t)pos[t * 2 + 1] * DD + d);
  const float o0 = g0 * bf2f((uint16_t)u0) + g1 * bf2f((uint16_t)u1);
  const float o1 = g0 * bf2f((uint16_t)(u0 >> 16)) + g1 * bf2f((uint16_t)(u1 >> 16));
  *(float2*)(out + (size_t)t * DD + d) = make_float2(o0, o1);
}

extern "C" void kernel_launch(void* const* d_in, const int* in_sizes, int n_in,
                              void* d_out, int out_size, void* d_ws, size_t ws_size,
                              hipStream_t stream) {
  const float* x  = (const float*)d_in[0];
  const float* Wr = (const float*)d_in[1];
  const float* W1 = (const float*)d_in[2];
  const float* b1 = (const float*)d_in[3];
  const float* W2 = (const float*)d_in[4];
  const float* b2 = (const float*)d_in[5];
  float* out = (float*)d_out;

  // Workspace layout (NOTE: ybuf ALIASES xb+W1T — their lifetimes are disjoint:
  // xb/W1T are last read by FC1; ybuf is first written by FC2 which is
  // stream-ordered after FC1. Keeps total ws ~235 MB, under the ~263 MB that
  // round 2 proved available; round 6's 274 MB overflowed ws -> GPU fault.)
  char* ws = (char*)d_ws;
  size_t o = 0;
  auto alloc = [&](size_t bytes) { size_t r = o; o += (bytes + 255) & ~(size_t)255; return r; };
  uint16_t* xb    = (uint16_t*)(ws + alloc((size_t)NT * DD * 2));       // 16 MB  [region A]
  uint16_t* W1T   = (uint16_t*)(ws + alloc((size_t)NE * FF * DD * 2));  // 32 MB  [region A] [E][F][D]
  uint16_t* ybuf  = (uint16_t*)ws;  // 36 MB, aliases region A (xb+W1T = 48 MB)
  uint16_t* W2T   = (uint16_t*)(ws + alloc((size_t)NE * DD * FF * 2));  // 32 MB  [E][D][F]
  uint16_t* h     = (uint16_t*)(ws + alloc((size_t)NPAL * FF * 2));     // 144 MB
  int*   cnt_part = (int*)(ws + alloc(64 * NE * 4));
  int*   f_part   = (int*)(ws + alloc(64 * NE * 4));
  float* P_part   = (float*)(ws + alloc(64 * NE * 4));
  int*   topi     = (int*)(ws + alloc((size_t)NT * 2 * 4));
  float* gatesb   = (float*)(ws + alloc((size_t)NT * 2 * 4));
  int*   pos      = (int*)(ws + alloc((size_t)NT * 2 * 4));
  int*   tokofp   = (int*)(ws + alloc((size_t)NPAL * 4));
  int*   counts   = (int*)(ws + alloc(NE * 4));
  int*   goff     = (int*)(ws + alloc((NE + 1) * 4));
  int*   cursor   = (int*)(ws + alloc(NE * 4));
  (void)ws_size; (void)in_sizes; (void)n_in; (void)out_size; (void)counts;

  k_zero<<<1, 256, 0, stream>>>(cnt_part, 3 * 64 * NE);  // cnt/f/P partials contiguous
  k_trans<<<dim3(FF / 32, DD / 32, NE), dim3(32, 8), 0, stream>>>(W1, W1T, DD, FF);
  k_trans<<<dim3(DD / 32, FF / 32, NE), dim3(32, 8), 0, stream>>>(W2, W2T, FF, DD);
  k_router<<<NT / 4, 256, 0, stream>>>(x, Wr, xb, topi, gatesb, cnt_part, f_part, P_part);
  k_reduce<<<1, 256, 0, stream>>>(cnt_part, f_part, P_part, counts, goff, cursor,
                                  tokofp, out + (size_t)NT * DD);
  k_build<<<NT / 256, 256, 0, stream>>>(topi, cursor, tokofp, pos);
  // FC1: 256x256 tile, 512 thr, per-wave 128x64   (reads xb, W1T; writes h)
  k_gemm<256, 256, 512, DD, FF, true>
      <<<dim3(FF / 256, MT256), 512, 0, stream>>>(xb, W1T, b1, h, goff, tokofp);
  // FC2: 128x128 tile, 256 thr, 2 blocks/CU       (reads h, W2T; writes ybuf over dead xb/W1T)
  k_gemm<128, 128, 256, FF, DD, false>
      <<<dim3(DD / 128, MT128), 256, 0, stream>>>(h, W2T, b2, ybuf, goff, tokofp);
  k_comb<<<NT, 256, 0, stream>>>(ybuf, pos, gatesb, out);
}

// Round 8
// 596.140 us; speedup vs baseline: 1.0635x; 1.0635x over previous
//
#include <hip/hip_runtime.h>
#include <cstdint>
#include <cstddef>

// Problem constants
#define NB 8
#define TT 2048
#define DD 512
#define FF 2048
#define NE 16
#define NT (NB*TT)              // 16384 tokens
#define NPOS (NT*2)             // 32768 dispatch slots (K=2)
#define MT256 (NPOS/256 + NE)   // 144 max 256-row M-tiles (per-expert ceil to 256)
#define NPAL (MT256*256)        // 36864 padded positions
#define MT128 (NPAL/128)        // 288 max 128-row M-tiles

typedef short v8s __attribute__((ext_vector_type(8)));   // 8 x bf16 bits (4 VGPRs)
typedef float v4f __attribute__((ext_vector_type(4)));

__device__ __forceinline__ uint16_t f2bf(float v) {
  union { float f; uint32_t u; } c; c.f = v;
  uint32_t r = (c.u + 0x7FFFu + ((c.u >> 16) & 1u)) >> 16;   // RNE
  return (uint16_t)r;
}
__device__ __forceinline__ float bf2f(uint16_t b) {
  union { uint32_t u; float f; } c; c.u = ((uint32_t)b) << 16;
  return c.f;
}
// jax.nn.gelu approximate=True: 0.5x(1+tanh(u)) == x * sigmoid(2u)
__device__ __forceinline__ float gelu_t(float x) {
  float u = 0.7978845608028654f * (x + 0.044715f * x * x * x);
  float e = __expf(-2.0f * u);
  return __fdividef(x, 1.0f + e);
}
__device__ __forceinline__ void gl_lds16(const void* g, void* l) {
  __builtin_amdgcn_global_load_lds(
      (const __attribute__((address_space(1))) uint32_t*)g,
      (__attribute__((address_space(3))) uint32_t*)l, 16, 0, 0);
}

// ---------------- zero small scratch ----------------
__global__ void k_zero(int* p, int n) {
  for (int i = threadIdx.x; i < n; i += 256) p[i] = 0;
}

// ---------------- transpose + convert weights: dst[e][c][r] = src[e][r][c] ----------------
// write phase vectorized: each thread stores ushort4 (8 B) along the dst row.
__global__ __launch_bounds__(256) void k_trans(const float* __restrict__ src,
                                               uint16_t* __restrict__ dst,
                                               int rows, int cols) {
  __shared__ float t[32][33];
  const size_t eo = (size_t)blockIdx.z * rows * cols;
  const float* s = src + eo;
  uint16_t* d = dst + eo;
  int c0 = blockIdx.x * 32, r0 = blockIdx.y * 32;
  int tx = threadIdx.x, ty = threadIdx.y;
#pragma unroll
  for (int i = 0; i < 4; ++i)
    t[ty + i * 8][tx] = s[(size_t)(r0 + ty + i * 8) * cols + c0 + tx];
  __syncthreads();
  const int ft = ty * 32 + tx;
  const int dr = ft >> 3;          // dst row within tile (= src col)
  const int dcg = (ft & 7) * 4;    // dst col group (= src row), 4 wide
  ushort4 o;
  o.x = f2bf(t[dcg + 0][dr]); o.y = f2bf(t[dcg + 1][dr]);
  o.z = f2bf(t[dcg + 2][dr]); o.w = f2bf(t[dcg + 3][dr]);
  *(ushort4*)(d + (size_t)(c0 + dr) * rows + r0 + dcg) = o;
}

// ---------------- router (fp64 logits for exact top-k agreement) + x->bf16 ----------------
__global__ __launch_bounds__(256) void k_router(
    const float* __restrict__ x, const float* __restrict__ Wr,
    uint16_t* __restrict__ xb,
    int* __restrict__ topi, float* __restrict__ gates,
    int* __restrict__ cnt_part, int* __restrict__ f_part, float* __restrict__ P_part) {
  __shared__ int s_cnt[NE]; __shared__ int s_f[NE]; __shared__ float s_P[NE];
  const int tid = threadIdx.x;
  if (tid < NE) { s_cnt[tid] = 0; s_f[tid] = 0; s_P[tid] = 0.f; }
  __syncthreads();
  const int wid = tid >> 6, lane = tid & 63;
  const int t = blockIdx.x * 4 + wid;
  const float* xr = x + (size_t)t * DD + lane * 8;
  double pe[NE];
#pragma unroll
  for (int e = 0; e < NE; ++e) pe[e] = 0.0;
  float xv8[8];
#pragma unroll
  for (int j = 0; j < 8; ++j) xv8[j] = xr[j];
#pragma unroll
  for (int j = 0; j < 8; ++j) {
    const double xv = (double)xv8[j];
    const float* wr = Wr + (size_t)(lane * 8 + j) * NE;
#pragma unroll
    for (int e = 0; e < NE; ++e) pe[e] += xv * (double)wr[e];
  }
  // write bf16 copy of x (fused former k_cvt_x)
  {
    ushort4 o0, o1;
    o0.x = f2bf(xv8[0]); o0.y = f2bf(xv8[1]); o0.z = f2bf(xv8[2]); o0.w = f2bf(xv8[3]);
    o1.x = f2bf(xv8[4]); o1.y = f2bf(xv8[5]); o1.z = f2bf(xv8[6]); o1.w = f2bf(xv8[7]);
    uint16_t* xo = xb + (size_t)t * DD + lane * 8;
    *(ushort4*)xo = o0; *(ushort4*)(xo + 4) = o1;
  }
#pragma unroll
  for (int m = 1; m < 64; m <<= 1) {
#pragma unroll
    for (int e = 0; e < NE; ++e) pe[e] += __shfl_xor(pe[e], m, 64);
  }
  if (lane == 0) {
    double mx = pe[0];
#pragma unroll
    for (int e = 1; e < NE; ++e) mx = fmax(mx, pe[e]);
    double s = 0.0, pr[NE];
#pragma unroll
    for (int e = 0; e < NE; ++e) { pr[e] = exp(pe[e] - mx); s += pr[e]; }
    const double inv = 1.0 / s;
    int i0 = 0; double v0 = pe[0];
#pragma unroll
    for (int e = 1; e < NE; ++e) if (pe[e] > v0) { v0 = pe[e]; i0 = e; }
    int i1 = -1; double v1 = -1.0e300;
#pragma unroll
    for (int e = 0; e < NE; ++e) if (e != i0 && pe[e] > v1) { v1 = pe[e]; i1 = e; }
    const double g0 = 1.0 / (1.0 + exp(v1 - v0));
    topi[t * 2] = i0; topi[t * 2 + 1] = i1;
    gates[t * 2] = (float)g0; gates[t * 2 + 1] = (float)(1.0 - g0);
    atomicAdd(&s_cnt[i0], 1); atomicAdd(&s_cnt[i1], 1);
    atomicAdd(&s_f[i0], 1);
#pragma unroll
    for (int e = 0; e < NE; ++e) atomicAdd(&s_P[e], (float)(pr[e] * inv));
  }
  __syncthreads();
  if (tid < NE) {
    const int slot = (blockIdx.x & 63) * NE + tid;
    if (s_cnt[tid]) atomicAdd(&cnt_part[slot], s_cnt[tid]);
    if (s_f[tid]) atomicAdd(&f_part[slot], s_f[tid]);
    atomicAdd(&P_part[slot], s_P[tid]);
  }
}

// ---------------- reduce partials -> counts, 256-aligned offsets, aux loss, pad fill ----------------
__global__ __launch_bounds__(256) void k_reduce(
    const int* __restrict__ cnt_part, const int* __restrict__ f_part,
    const float* __restrict__ P_part, int* __restrict__ counts,
    int* __restrict__ goff, int* __restrict__ cursor,
    int* __restrict__ tokofp, float* __restrict__ aux_out) {
  __shared__ int sc[NE]; __shared__ int sgo[NE + 1]; __shared__ double sterm[NE];
  const int tid = threadIdx.x;
  if (tid < NE) {
    int c = 0, f = 0; float P = 0.f;
    for (int s = 0; s < 64; ++s) {
      c += cnt_part[s * NE + tid]; f += f_part[s * NE + tid]; P += P_part[s * NE + tid];
    }
    counts[tid] = c; sc[tid] = c;
    sterm[tid] = ((double)f / NT) * ((double)P / NT);
  }
  __syncthreads();
  if (tid == 0) {
    double a = 0;
    for (int e = 0; e < NE; ++e) a += sterm[e];
    *aux_out = (float)(NE * a);
    int o = 0; sgo[0] = 0;
    for (int e = 0; e < NE; ++e) { o += ((sc[e] + 255) >> 8) << 8; sgo[e + 1] = o; }
    for (int e = 0; e <= NE; ++e) goff[e] = sgo[e];
    for (int e = 0; e < NE; ++e) cursor[e] = sgo[e];
  }
  __syncthreads();
  for (int e = 0; e < NE; ++e) {
    const int st = sgo[e] + sc[e], en = sgo[e + 1];
    for (int i = st + tid; i < en; i += 256) tokofp[i] = 0;  // padded rows gather token 0
  }
}

// ---------------- build per-expert token lists ----------------
__global__ __launch_bounds__(256) void k_build(const int* __restrict__ topi,
                                               int* __restrict__ cursor,
                                               int* __restrict__ tokofp,
                                               int* __restrict__ pos) {
  __shared__ int scnt[NE]; __shared__ int sbase[NE];
  const int tid = threadIdx.x;
  const int t = blockIdx.x * 256 + tid;
  if (tid < NE) scnt[tid] = 0;
  __syncthreads();
  const int e0 = topi[t * 2], e1 = topi[t * 2 + 1];
  const int r0 = atomicAdd(&scnt[e0], 1);
  const int r1 = atomicAdd(&scnt[e1], 1);
  __syncthreads();
  if (tid < NE) sbase[tid] = scnt[tid] ? atomicAdd(&cursor[tid], scnt[tid]) : 0;
  __syncthreads();
  const int p0 = sbase[e0] + r0, p1 = sbase[e1] + r1;
  tokofp[p0] = t; tokofp[p1] = t;
  pos[t * 2] = p0; pos[t * 2 + 1] = p1;
}

// ---------------- BMxBNx64 bf16 MFMA GEMM, double-buffered 2-phase pipeline ----------------
// GATHER_GELU=true : A = xb gathered via tokofp (K=512),  epilogue gelu -> h
// GATHER_GELU=false: A = h rows direct (K=2048),          epilogue bias -> ybuf
// LDS rows are 64 bf16 (128 B); 16-B slots XOR-swizzled by (row&7) on BOTH the
// pre-swizzled global source and the ds_read address (linear gl_lds dest).
// MFMA is called with SWAPPED operands: mfma(bf, af) -> D'[n][m] == C[m][n],
// so each lane holds row=lane&15 and 4 CONSECUTIVE cols -> packed ushort4
// stores (8 B/lane, 32 B per lane-quad) in the epilogue. Bitwise-identical
// accumulation to the unswapped form (same k-order per element).
template <int BM, int BN, int NTHR, int KDIM, int NDIM, bool GATHER_GELU>
__global__ __launch_bounds__(NTHR, 2) void k_gemm(
    const uint16_t* __restrict__ Abase, const uint16_t* __restrict__ Bt,
    const float* __restrict__ bias, uint16_t* __restrict__ Cout,
    const int* __restrict__ goff, const int* __restrict__ tokofp) {
  constexpr int WAVES = NTHR / 64;
  constexpr int WN = (WAVES == 8) ? 4 : 2;
  constexpr int WM = WAVES / WN;
  constexpr int MF = BM / (WM * 16);        // m-fragments per wave
  constexpr int NF = BN / (WN * 16);        // n-fragments per wave
  constexpr int LA = BM * 64 / (NTHR * 8);  // gl_lds16 per thread for A per K-tile
  constexpr int LB = BN * 64 / (NTHR * 8);
  constexpr int NKT = KDIM / 64;
  __shared__ __align__(16) uint16_t As[2 * BM * 64];
  __shared__ __align__(16) uint16_t Bs[2 * BN * 64];

  const int ntiles = goff[NE] / BM;
  const int gy = blockIdx.y;
  if (gy >= ntiles) return;
  int e = 0;
#pragma unroll
  for (int i = 1; i < NE; ++i) if (gy * BM >= goff[i]) e = i;
  const int row0 = gy * BM;
  const int n0 = blockIdx.x * BN;
  const int tid = threadIdx.x, lane = tid & 63;
  const int wid = tid >> 6;
  const int wm = wid / WN, wn = wid % WN;

  // ---- staging pointers (linear LDS dest, pre-swizzled global source) ----
  const uint16_t* Be = Bt + (size_t)e * ((size_t)NDIM * KDIM);
  const uint16_t* ag[LA]; const uint16_t* bg[LB];
  int ldsOffA[LA], ldsOffB[LB];
#pragma unroll
  for (int r = 0; r < LA; ++r) {
    const int flat = r * NTHR + tid;
    const int row = flat >> 3, slot = flat & 7;
    ldsOffA[r] = flat * 8;
    size_t srow;
    if (GATHER_GELU) srow = (size_t)tokofp[row0 + row];
    else             srow = (size_t)(row0 + row);
    ag[r] = Abase + srow * KDIM + (slot ^ (row & 7)) * 8;
  }
#pragma unroll
  for (int r = 0; r < LB; ++r) {
    const int flat = r * NTHR + tid;
    const int row = flat >> 3, slot = flat & 7;
    ldsOffB[r] = flat * 8;
    bg[r] = Be + (size_t)(n0 + row) * KDIM + (slot ^ (row & 7)) * 8;
  }

  // ---- fragment read offsets: XOR term is uniformly (lane&7)<<4 ----
  const int kswz[2] = {
      (((lane >> 4) << 4)) ^ ((lane & 7) << 4),
      (64 + ((lane >> 4) << 4)) ^ ((lane & 7) << 4)};
  const int aRow = (wm * (MF * 16) + (lane & 15)) * 128;  // byte offset of frag row
  const int bRow = (wn * (NF * 16) + (lane & 15)) * 128;

  v4f acc[MF][NF];
#pragma unroll
  for (int i = 0; i < MF; ++i)
#pragma unroll
    for (int j = 0; j < NF; ++j) acc[i][j] = (v4f){0.f, 0.f, 0.f, 0.f};

  // ---- prologue: stage K-tile 0 into buffer 0 ----
#pragma unroll
  for (int r = 0; r < LA; ++r) gl_lds16(ag[r], As + ldsOffA[r]);
#pragma unroll
  for (int r = 0; r < LB; ++r) gl_lds16(bg[r], Bs + ldsOffB[r]);
  __syncthreads();   // compiler emits vmcnt(0) drain before barrier

  int cur = 0;
  for (int kt = 0; kt < NKT; ++kt) {
    // issue next K-tile's loads into the other buffer BEFORE compute
    if (kt + 1 < NKT) {
      uint16_t* an = As + (cur ^ 1) * (BM * 64);
      uint16_t* bn = Bs + (cur ^ 1) * (BN * 64);
#pragma unroll
      for (int r = 0; r < LA; ++r) gl_lds16(ag[r] + (kt + 1) * 64, an + ldsOffA[r]);
#pragma unroll
      for (int r = 0; r < LB; ++r) gl_lds16(bg[r] + (kt + 1) * 64, bn + ldsOffB[r]);
    }
    const char* ab = (const char*)(As + cur * (BM * 64));
    const char* bb = (const char*)(Bs + cur * (BN * 64));
#pragma unroll
    for (int kk = 0; kk < 2; ++kk) {
      v8s af[MF], bf[NF];
#pragma unroll
      for (int f = 0; f < MF; ++f)
        af[f] = *(const v8s*)(ab + aRow + f * 2048 + kswz[kk]);
#pragma unroll
      for (int f = 0; f < NF; ++f)
        bf[f] = *(const v8s*)(bb + bRow + f * 2048 + kswz[kk]);
#pragma unroll
      for (int m = 0; m < MF; ++m)
#pragma unroll
        for (int n = 0; n < NF; ++n)
          acc[m][n] = __builtin_amdgcn_mfma_f32_16x16x32_bf16(bf[n], af[m], acc[m][n], 0, 0, 0);
    }
    __syncthreads();   // drains next-tile vmcnt + swaps buffer roles
    cur ^= 1;
  }

  // ---- epilogue (swapped layout): row = lane&15, cols = (lane>>4)*4 + j ----
#pragma unroll
  for (int fm = 0; fm < MF; ++fm) {
    const int row = row0 + wm * (MF * 16) + fm * 16 + (lane & 15);
    uint16_t* crow = Cout + (size_t)row * NDIM;
#pragma unroll
    for (int fn = 0; fn < NF; ++fn) {
      const int colb = n0 + wn * (NF * 16) + fn * 16 + ((lane >> 4) << 2);
      const float4 bv = *(const float4*)(bias + e * NDIM + colb);
      float v0 = acc[fm][fn][0] + bv.x;
      float v1 = acc[fm][fn][1] + bv.y;
      float v2 = acc[fm][fn][2] + bv.z;
      float v3 = acc[fm][fn][3] + bv.w;
      if (GATHER_GELU) { v0 = gelu_t(v0); v1 = gelu_t(v1); v2 = gelu_t(v2); v3 = gelu_t(v3); }
      ushort4 o; o.x = f2bf(v0); o.y = f2bf(v1); o.z = f2bf(v2); o.w = f2bf(v3);
      *(ushort4*)(crow + colb) = o;
    }
  }
}

// ---------------- combine: out[t] = g0*y[pos0] + g1*y[pos1] ----------------
__global__ __launch_bounds__(256) void k_comb(const uint16_t* __restrict__ ybuf,
                                              const int* __restrict__ pos,
                                              const float* __restrict__ gates,
                                              float* __restrict__ out) {
  const int t = blockIdx.x;
  const int d = threadIdx.x * 2;
  const float g0 = gates[t * 2], g1 = gates[t * 2 + 1];
  const uint32_t u0 = *(const uint32_t*)(ybuf + (size_t)pos[t * 2] * DD + d);
  const uint32_t u1 = *(const uint32_t*)(ybuf + (size_t)pos[t * 2 + 1] * DD + d);
  const float o0 = g0 * bf2f((uint16_t)u0) + g1 * bf2f((uint16_t)u1);
  const float o1 = g0 * bf2f((uint16_t)(u0 >> 16)) + g1 * bf2f((uint16_t)(u1 >> 16));
  *(float2*)(out + (size_t)t * DD + d) = make_float2(o0, o1);
}

extern "C" void kernel_launch(void* const* d_in, const int* in_sizes, int n_in,
                              void* d_out, int out_size, void* d_ws, size_t ws_size,
                              hipStream_t stream) {
  const float* x  = (const float*)d_in[0];
  const float* Wr = (const float*)d_in[1];
  const float* W1 = (const float*)d_in[2];
  const float* b1 = (const float*)d_in[3];
  const float* W2 = (const float*)d_in[4];
  const float* b2 = (const float*)d_in[5];
  float* out = (float*)d_out;

  // Workspace layout (NOTE: ybuf ALIASES xb+W1T — their lifetimes are disjoint:
  // xb/W1T are last read by FC1; ybuf is first written by FC2 which is
  // stream-ordered after FC1. Keeps total ws ~235 MB; round 6's 274 MB overflowed.)
  char* ws = (char*)d_ws;
  size_t o = 0;
  auto alloc = [&](size_t bytes) { size_t r = o; o += (bytes + 255) & ~(size_t)255; return r; };
  uint16_t* xb    = (uint16_t*)(ws + alloc((size_t)NT * DD * 2));       // 16 MB  [region A]
  uint16_t* W1T   = (uint16_t*)(ws + alloc((size_t)NE * FF * DD * 2));  // 32 MB  [region A] [E][F][D]
  uint16_t* ybuf  = (uint16_t*)ws;  // 36 MB, aliases region A (xb+W1T = 48 MB)
  uint16_t* W2T   = (uint16_t*)(ws + alloc((size_t)NE * DD * FF * 2));  // 32 MB  [E][D][F]
  uint16_t* h     = (uint16_t*)(ws + alloc((size_t)NPAL * FF * 2));     // 144 MB
  int*   cnt_part = (int*)(ws + alloc(64 * NE * 4));
  int*   f_part   = (int*)(ws + alloc(64 * NE * 4));
  float* P_part   = (float*)(ws + alloc(64 * NE * 4));
  int*   topi     = (int*)(ws + alloc((size_t)NT * 2 * 4));
  float* gatesb   = (float*)(ws + alloc((size_t)NT * 2 * 4));
  int*   pos      = (int*)(ws + alloc((size_t)NT * 2 * 4));
  int*   tokofp   = (int*)(ws + alloc((size_t)NPAL * 4));
  int*   counts   = (int*)(ws + alloc(NE * 4));
  int*   goff     = (int*)(ws + alloc((NE + 1) * 4));
  int*   cursor   = (int*)(ws + alloc(NE * 4));
  (void)ws_size; (void)in_sizes; (void)n_in; (void)out_size; (void)counts;

  k_zero<<<1, 256, 0, stream>>>(cnt_part, 3 * 64 * NE);  // cnt/f/P partials contiguous
  k_trans<<<dim3(FF / 32, DD / 32, NE), dim3(32, 8), 0, stream>>>(W1, W1T, DD, FF);
  k_trans<<<dim3(DD / 32, FF / 32, NE), dim3(32, 8), 0, stream>>>(W2, W2T, FF, DD);
  k_router<<<NT / 4, 256, 0, stream>>>(x, Wr, xb, topi, gatesb, cnt_part, f_part, P_part);
  k_reduce<<<1, 256, 0, stream>>>(cnt_part, f_part, P_part, counts, goff, cursor,
                                  tokofp, out + (size_t)NT * DD);
  k_build<<<NT / 256, 256, 0, stream>>>(topi, cursor, tokofp, pos);
  // FC1: 256x256 tile, 512 thr, per-wave 128x64   (reads xb, W1T; writes h)
  k_gemm<256, 256, 512, DD, FF, true>
      <<<dim3(FF / 256, MT256), 512, 0, stream>>>(xb, W1T, b1, h, goff, tokofp);
  // FC2: 128x128 tile, 256 thr, 2 blocks/CU       (reads h, W2T; writes ybuf over dead xb/W1T)
  k_gemm<128, 128, 256, FF, DD, false>
      <<<dim3(DD / 128, MT128), 256, 0, stream>>>(h, W2T, b2, ybuf, goff, tokofp);
  k_comb<<<NT, 256, 0, stream>>>(ybuf, pos, gatesb, out);
}

// Round 10
// 578.239 us; speedup vs baseline: 1.0964x; 1.0310x over previous
//
#include <hip/hip_runtime.h>
#include <cstdint>
#include <cstddef>

// Problem constants
#define NB 8
#define TT 2048
#define DD 512
#define FF 2048
#define NE 16
#define NT (NB*TT)              // 16384 tokens
#define NPOS (NT*2)             // 32768 dispatch slots (K=2)
#define MT256 (NPOS/256 + NE)   // 144 max 256-row M-tiles (per-expert ceil to 256)
#define NPAL (MT256*256)        // 36864 padded positions

typedef short v8s __attribute__((ext_vector_type(8)));   // 8 x bf16 bits (4 VGPRs)
typedef float v4f __attribute__((ext_vector_type(4)));

__device__ __forceinline__ uint16_t f2bf(float v) {
  union { float f; uint32_t u; } c; c.f = v;
  uint32_t r = (c.u + 0x7FFFu + ((c.u >> 16) & 1u)) >> 16;   // RNE
  return (uint16_t)r;
}
__device__ __forceinline__ float bf2f(uint16_t b) {
  union { uint32_t u; float f; } c; c.u = ((uint32_t)b) << 16;
  return c.f;
}
// jax.nn.gelu approximate=True: 0.5x(1+tanh(u)) == x * sigmoid(2u)
__device__ __forceinline__ float gelu_t(float x) {
  float u = 0.7978845608028654f * (x + 0.044715f * x * x * x);
  float e = __expf(-2.0f * u);
  return __fdividef(x, 1.0f + e);
}
__device__ __forceinline__ void gl_lds16(const void* g, void* l) {
  __builtin_amdgcn_global_load_lds(
      (const __attribute__((address_space(1))) uint32_t*)g,
      (__attribute__((address_space(3))) uint32_t*)l, 16, 0, 0);
}

// ---------------- zero small scratch ----------------
__global__ void k_zero(int* p, int n) {
  for (int i = threadIdx.x; i < n; i += 256) p[i] = 0;
}

// ---------------- transpose + convert weights: dst[e][c][r] = src[e][r][c] ----------------
// write phase vectorized: each thread stores ushort4 (8 B) along the dst row.
__global__ __launch_bounds__(256) void k_trans(const float* __restrict__ src,
                                               uint16_t* __restrict__ dst,
                                               int rows, int cols) {
  __shared__ float t[32][33];
  const size_t eo = (size_t)blockIdx.z * rows * cols;
  const float* s = src + eo;
  uint16_t* d = dst + eo;
  int c0 = blockIdx.x * 32, r0 = blockIdx.y * 32;
  int tx = threadIdx.x, ty = threadIdx.y;
#pragma unroll
  for (int i = 0; i < 4; ++i)
    t[ty + i * 8][tx] = s[(size_t)(r0 + ty + i * 8) * cols + c0 + tx];
  __syncthreads();
  const int ft = ty * 32 + tx;
  const int dr = ft >> 3;          // dst row within tile (= src col)
  const int dcg = (ft & 7) * 4;    // dst col group (= src row), 4 wide
  ushort4 o;
  o.x = f2bf(t[dcg + 0][dr]); o.y = f2bf(t[dcg + 1][dr]);
  o.z = f2bf(t[dcg + 2][dr]); o.w = f2bf(t[dcg + 3][dr]);
  *(ushort4*)(d + (size_t)(c0 + dr) * rows + r0 + dcg) = o;
}

// ---------------- router (fp64 logits for exact top-k agreement) + x->bf16 ----------------
__global__ __launch_bounds__(256) void k_router(
    const float* __restrict__ x, const float* __restrict__ Wr,
    uint16_t* __restrict__ xb,
    int* __restrict__ topi, float* __restrict__ gates,
    int* __restrict__ cnt_part, int* __restrict__ f_part, float* __restrict__ P_part) {
  __shared__ int s_cnt[NE]; __shared__ int s_f[NE]; __shared__ float s_P[NE];
  const int tid = threadIdx.x;
  if (tid < NE) { s_cnt[tid] = 0; s_f[tid] = 0; s_P[tid] = 0.f; }
  __syncthreads();
  const int wid = tid >> 6, lane = tid & 63;
  const int t = blockIdx.x * 4 + wid;
  const float* xr = x + (size_t)t * DD + lane * 8;
  double pe[NE];
#pragma unroll
  for (int e = 0; e < NE; ++e) pe[e] = 0.0;
  float xv8[8];
#pragma unroll
  for (int j = 0; j < 8; ++j) xv8[j] = xr[j];
#pragma unroll
  for (int j = 0; j < 8; ++j) {
    const double xv = (double)xv8[j];
    const float* wr = Wr + (size_t)(lane * 8 + j) * NE;
#pragma unroll
    for (int e = 0; e < NE; ++e) pe[e] += xv * (double)wr[e];
  }
  // write bf16 copy of x (fused former k_cvt_x)
  {
    ushort4 o0, o1;
    o0.x = f2bf(xv8[0]); o0.y = f2bf(xv8[1]); o0.z = f2bf(xv8[2]); o0.w = f2bf(xv8[3]);
    o1.x = f2bf(xv8[4]); o1.y = f2bf(xv8[5]); o1.z = f2bf(xv8[6]); o1.w = f2bf(xv8[7]);
    uint16_t* xo = xb + (size_t)t * DD + lane * 8;
    *(ushort4*)xo = o0; *(ushort4*)(xo + 4) = o1;
  }
#pragma unroll
  for (int m = 1; m < 64; m <<= 1) {
#pragma unroll
    for (int e = 0; e < NE; ++e) pe[e] += __shfl_xor(pe[e], m, 64);
  }
  if (lane == 0) {
    double mx = pe[0];
#pragma unroll
    for (int e = 1; e < NE; ++e) mx = fmax(mx, pe[e]);
    double s = 0.0, pr[NE];
#pragma unroll
    for (int e = 0; e < NE; ++e) { pr[e] = exp(pe[e] - mx); s += pr[e]; }
    const double inv = 1.0 / s;
    int i0 = 0; double v0 = pe[0];
#pragma unroll
    for (int e = 1; e < NE; ++e) if (pe[e] > v0) { v0 = pe[e]; i0 = e; }
    int i1 = -1; double v1 = -1.0e300;
#pragma unroll
    for (int e = 0; e < NE; ++e) if (e != i0 && pe[e] > v1) { v1 = pe[e]; i1 = e; }
    const double g0 = 1.0 / (1.0 + exp(v1 - v0));
    topi[t * 2] = i0; topi[t * 2 + 1] = i1;
    gates[t * 2] = (float)g0; gates[t * 2 + 1] = (float)(1.0 - g0);
    atomicAdd(&s_cnt[i0], 1); atomicAdd(&s_cnt[i1], 1);
    atomicAdd(&s_f[i0], 1);
#pragma unroll
    for (int e = 0; e < NE; ++e) atomicAdd(&s_P[e], (float)(pr[e] * inv));
  }
  __syncthreads();
  if (tid < NE) {
    const int slot = (blockIdx.x & 63) * NE + tid;
    if (s_cnt[tid]) atomicAdd(&cnt_part[slot], s_cnt[tid]);
    if (s_f[tid]) atomicAdd(&f_part[slot], s_f[tid]);
    atomicAdd(&P_part[slot], s_P[tid]);
  }
}

// ---------------- reduce partials -> counts, 256-aligned offsets, aux loss, pad fill ----------------
__global__ __launch_bounds__(256) void k_reduce(
    const int* __restrict__ cnt_part, const int* __restrict__ f_part,
    const float* __restrict__ P_part, int* __restrict__ counts,
    int* __restrict__ goff, int* __restrict__ cursor,
    int* __restrict__ tokofp, float* __restrict__ aux_out) {
  __shared__ int sc[NE]; __shared__ int sgo[NE + 1]; __shared__ double sterm[NE];
  const int tid = threadIdx.x;
  if (tid < NE) {
    int c = 0, f = 0; float P = 0.f;
    for (int s = 0; s < 64; ++s) {
      c += cnt_part[s * NE + tid]; f += f_part[s * NE + tid]; P += P_part[s * NE + tid];
    }
    counts[tid] = c; sc[tid] = c;
    sterm[tid] = ((double)f / NT) * ((double)P / NT);
  }
  __syncthreads();
  if (tid == 0) {
    double a = 0;
    for (int e = 0; e < NE; ++e) a += sterm[e];
    *aux_out = (float)(NE * a);
    int o = 0; sgo[0] = 0;
    for (int e = 0; e < NE; ++e) { o += ((sc[e] + 255) >> 8) << 8; sgo[e + 1] = o; }
    for (int e = 0; e <= NE; ++e) goff[e] = sgo[e];
    for (int e = 0; e < NE; ++e) cursor[e] = sgo[e];
  }
  __syncthreads();
  for (int e = 0; e < NE; ++e) {
    const int st = sgo[e] + sc[e], en = sgo[e + 1];
    for (int i = st + tid; i < en; i += 256) tokofp[i] = 0;  // padded rows gather token 0
  }
}

// ---------------- build per-expert token lists ----------------
__global__ __launch_bounds__(256) void k_build(const int* __restrict__ topi,
                                               int* __restrict__ cursor,
                                               int* __restrict__ tokofp,
                                               int* __restrict__ pos) {
  __shared__ int scnt[NE]; __shared__ int sbase[NE];
  const int tid = threadIdx.x;
  const int t = blockIdx.x * 256 + tid;
  if (tid < NE) scnt[tid] = 0;
  __syncthreads();
  const int e0 = topi[t * 2], e1 = topi[t * 2 + 1];
  const int r0 = atomicAdd(&scnt[e0], 1);
  const int r1 = atomicAdd(&scnt[e1], 1);
  __syncthreads();
  if (tid < NE) sbase[tid] = scnt[tid] ? atomicAdd(&cursor[tid], scnt[tid]) : 0;
  __syncthreads();
  const int p0 = sbase[e0] + r0, p1 = sbase[e1] + r1;
  tokofp[p0] = t; tokofp[p1] = t;
  pos[t * 2] = p0; pos[t * 2 + 1] = p1;
}

// ---------------- 256x256x64 bf16 MFMA GEMM, double-buffered 2-phase pipeline ----------------
// GATHER_GELU=true : A = xb gathered via tokofp (K=512),  epilogue gelu -> h
// GATHER_GELU=false: A = h rows direct (K=2048),          epilogue bias -> ybuf
// LDS rows are 64 bf16 (128 B); 16-B slots XOR-swizzled by (row&7) on BOTH the
// pre-swizzled global source and the ds_read address (linear gl_lds dest).
// MFMA uses SWAPPED operands: mfma(bf, af) -> lane holds row=lane&15, 4
// consecutive cols -> packed ushort4 epilogue stores.
// T1 XCD-chunked blockIdx swizzle: consecutive LOGICAL tiles (which share the
// A-panel / expert weight panel) map to the same XCD (hw round-robins raw bid
// across 8 XCDs). Requires NWG % 8 == 0 (both instantiations satisfy).
template <int BM, int BN, int NTHR, int KDIM, int NDIM, int NX, int GY, bool GATHER_GELU>
__global__ __launch_bounds__(NTHR, 2) void k_gemm(
    const uint16_t* __restrict__ Abase, const uint16_t* __restrict__ Bt,
    const float* __restrict__ bias, uint16_t* __restrict__ Cout,
    const int* __restrict__ goff, const int* __restrict__ tokofp) {
  constexpr int WAVES = NTHR / 64;
  constexpr int WN = (WAVES == 8) ? 4 : 2;
  constexpr int WM = WAVES / WN;
  constexpr int MF = BM / (WM * 16);        // m-fragments per wave
  constexpr int NF = BN / (WN * 16);        // n-fragments per wave
  constexpr int LA = BM * 64 / (NTHR * 8);  // gl_lds16 per thread for A per K-tile
  constexpr int LB = BN * 64 / (NTHR * 8);
  constexpr int NKT = KDIM / 64;
  constexpr int NWG = NX * GY;
  constexpr int CPX = NWG / 8;
  static_assert(NWG % 8 == 0, "XCD swizzle requires nwg % 8 == 0");
  __shared__ __align__(16) uint16_t As[2 * BM * 64];
  __shared__ __align__(16) uint16_t Bs[2 * BN * 64];

  // T1: raw bid -> logical tile index, chunked per XCD
  const int bid = (int)blockIdx.y * NX + (int)blockIdx.x;
  const int l = (bid & 7) * CPX + (bid >> 3);
  const int gy = l / NX;
  const int n0 = (l % NX) * BN;

  const int ntiles = goff[NE] / BM;
  if (gy >= ntiles) return;
  int e = 0;
#pragma unroll
  for (int i = 1; i < NE; ++i) if (gy * BM >= goff[i]) e = i;
  const int row0 = gy * BM;
  const int tid = threadIdx.x, lane = tid & 63;
  const int wid = tid >> 6;
  const int wm = wid / WN, wn = wid % WN;

  // ---- staging pointers (linear LDS dest, pre-swizzled global source) ----
  const uint16_t* Be = Bt + (size_t)e * ((size_t)NDIM * KDIM);
  const uint16_t* ag[LA]; const uint16_t* bg[LB];
  int ldsOffA[LA], ldsOffB[LB];
#pragma unroll
  for (int r = 0; r < LA; ++r) {
    const int flat = r * NTHR + tid;
    const int row = flat >> 3, slot = flat & 7;
    ldsOffA[r] = flat * 8;
    size_t srow;
    if (GATHER_GELU) srow = (size_t)tokofp[row0 + row];
    else             srow = (size_t)(row0 + row);
    ag[r] = Abase + srow * KDIM + (slot ^ (row & 7)) * 8;
  }
#pragma unroll
  for (int r = 0; r < LB; ++r) {
    const int flat = r * NTHR + tid;
    const int row = flat >> 3, slot = flat & 7;
    ldsOffB[r] = flat * 8;
    bg[r] = Be + (size_t)(n0 + row) * KDIM + (slot ^ (row & 7)) * 8;
  }

  // ---- fragment read offsets: XOR term is uniformly (lane&7)<<4 ----
  const int kswz[2] = {
      (((lane >> 4) << 4)) ^ ((lane & 7) << 4),
      (64 + ((lane >> 4) << 4)) ^ ((lane & 7) << 4)};
  const int aRow = (wm * (MF * 16) + (lane & 15)) * 128;  // byte offset of frag row
  const int bRow = (wn * (NF * 16) + (lane & 15)) * 128;

  v4f acc[MF][NF];
#pragma unroll
  for (int i = 0; i < MF; ++i)
#pragma unroll
    for (int j = 0; j < NF; ++j) acc[i][j] = (v4f){0.f, 0.f, 0.f, 0.f};

  // ---- prologue: stage K-tile 0 into buffer 0 ----
#pragma unroll
  for (int r = 0; r < LA; ++r) gl_lds16(ag[r], As + ldsOffA[r]);
#pragma unroll
  for (int r = 0; r < LB; ++r) gl_lds16(bg[r], Bs + ldsOffB[r]);
  __syncthreads();   // compiler emits vmcnt(0) drain before barrier

  int cur = 0;
  for (int kt = 0; kt < NKT; ++kt) {
    // issue next K-tile's loads into the other buffer BEFORE compute
    if (kt + 1 < NKT) {
      uint16_t* an = As + (cur ^ 1) * (BM * 64);
      uint16_t* bn = Bs + (cur ^ 1) * (BN * 64);
#pragma unroll
      for (int r = 0; r < LA; ++r) gl_lds16(ag[r] + (kt + 1) * 64, an + ldsOffA[r]);
#pragma unroll
      for (int r = 0; r < LB; ++r) gl_lds16(bg[r] + (kt + 1) * 64, bn + ldsOffB[r]);
    }
    const char* ab = (const char*)(As + cur * (BM * 64));
    const char* bb = (const char*)(Bs + cur * (BN * 64));
#pragma unroll
    for (int kk = 0; kk < 2; ++kk) {
      v8s af[MF], bf[NF];
#pragma unroll
      for (int f = 0; f < MF; ++f)
        af[f] = *(const v8s*)(ab + aRow + f * 2048 + kswz[kk]);
#pragma unroll
      for (int f = 0; f < NF; ++f)
        bf[f] = *(const v8s*)(bb + bRow + f * 2048 + kswz[kk]);
#pragma unroll
      for (int m = 0; m < MF; ++m)
#pragma unroll
        for (int n = 0; n < NF; ++n)
          acc[m][n] = __builtin_amdgcn_mfma_f32_16x16x32_bf16(bf[n], af[m], acc[m][n], 0, 0, 0);
    }
    __syncthreads();   // drains next-tile vmcnt + swaps buffer roles
    cur ^= 1;
  }

  // ---- epilogue (swapped layout): row = lane&15, cols = (lane>>4)*4 + j ----
#pragma unroll
  for (int fm = 0; fm < MF; ++fm) {
    const int row = row0 + wm * (MF * 16) + fm * 16 + (lane & 15);
    uint16_t* crow = Cout + (size_t)row * NDIM;
#pragma unroll
    for (int fn = 0; fn < NF; ++fn) {
      const int colb = n0 + wn * (NF * 16) + fn * 16 + ((lane >> 4) << 2);
      const float4 bv = *(const float4*)(bias + e * NDIM + colb);
      float v0 = acc[fm][fn][0] + bv.x;
      float v1 = acc[fm][fn][1] + bv.y;
      float v2 = acc[fm][fn][2] + bv.z;
      float v3 = acc[fm][fn][3] + bv.w;
      if (GATHER_GELU) { v0 = gelu_t(v0); v1 = gelu_t(v1); v2 = gelu_t(v2); v3 = gelu_t(v3); }
      ushort4 o; o.x = f2bf(v0); o.y = f2bf(v1); o.z = f2bf(v2); o.w = f2bf(v3);
      *(ushort4*)(crow + colb) = o;
    }
  }
}

// ---------------- combine: out[t] = g0*y[pos0] + g1*y[pos1] ----------------
__global__ __launch_bounds__(256) void k_comb(const uint16_t* __restrict__ ybuf,
                                              const int* __restrict__ pos,
                                              const float* __restrict__ gates,
                                              float* __restrict__ out) {
  const int t = blockIdx.x;
  const int d = threadIdx.x * 2;
  const float g0 = gates[t * 2], g1 = gates[t * 2 + 1];
  const uint32_t u0 = *(const uint32_t*)(ybuf + (size_t)pos[t * 2] * DD + d);
  const uint32_t u1 = *(const uint32_t*)(ybuf + (size_t)pos[t * 2 + 1] * DD + d);
  const float o0 = g0 * bf2f((uint16_t)u0) + g1 * bf2f((uint16_t)u1);
  const float o1 = g0 * bf2f((uint16_t)(u0 >> 16)) + g1 * bf2f((uint16_t)(u1 >> 16));
  *(float2*)(out + (size_t)t * DD + d) = make_float2(o0, o1);
}

extern "C" void kernel_launch(void* const* d_in, const int* in_sizes, int n_in,
                              void* d_out, int out_size, void* d_ws, size_t ws_size,
                              hipStream_t stream) {
  const float* x  = (const float*)d_in[0];
  const float* Wr = (const float*)d_in[1];
  const float* W1 = (const float*)d_in[2];
  const float* b1 = (const float*)d_in[3];
  const float* W2 = (const float*)d_in[4];
  const float* b2 = (const float*)d_in[5];
  float* out = (float*)d_out;

  // Workspace layout (NOTE: ybuf ALIASES xb+W1T — their lifetimes are disjoint:
  // xb/W1T are last read by FC1; ybuf is first written by FC2 which is
  // stream-ordered after FC1. Keeps total ws ~235 MB; round 6's 274 MB overflowed.)
  char* ws = (char*)d_ws;
  size_t o = 0;
  auto alloc = [&](size_t bytes) { size_t r = o; o += (bytes + 255) & ~(size_t)255; return r; };
  uint16_t* xb    = (uint16_t*)(ws + alloc((size_t)NT * DD * 2));       // 16 MB  [region A]
  uint16_t* W1T   = (uint16_t*)(ws + alloc((size_t)NE * FF * DD * 2));  // 32 MB  [region A] [E][F][D]
  uint16_t* ybuf  = (uint16_t*)ws;  // 36 MB, aliases region A (xb+W1T = 48 MB)
  uint16_t* W2T   = (uint16_t*)(ws + alloc((size_t)NE * DD * FF * 2));  // 32 MB  [E][D][F]
  uint16_t* h     = (uint16_t*)(ws + alloc((size_t)NPAL * FF * 2));     // 144 MB
  int*   cnt_part = (int*)(ws + alloc(64 * NE * 4));
  int*   f_part   = (int*)(ws + alloc(64 * NE * 4));
  float* P_part   = (float*)(ws + alloc(64 * NE * 4));
  int*   topi     = (int*)(ws + alloc((size_t)NT * 2 * 4));
  float* gatesb   = (float*)(ws + alloc((size_t)NT * 2 * 4));
  int*   pos      = (int*)(ws + alloc((size_t)NT * 2 * 4));
  int*   tokofp   = (int*)(ws + alloc((size_t)NPAL * 4));
  int*   counts   = (int*)(ws + alloc(NE * 4));
  int*   goff     = (int*)(ws + alloc((NE + 1) * 4));
  int*   cursor   = (int*)(ws + alloc(NE * 4));
  (void)ws_size; (void)in_sizes; (void)n_in; (void)out_size; (void)counts;

  k_zero<<<1, 256, 0, stream>>>(cnt_part, 3 * 64 * NE);  // cnt/f/P partials contiguous
  k_trans<<<dim3(FF / 32, DD / 32, NE), dim3(32, 8), 0, stream>>>(W1, W1T, DD, FF);
  k_trans<<<dim3(DD / 32, FF / 32, NE), dim3(32, 8), 0, stream>>>(W2, W2T, FF, DD);
  k_router<<<NT / 4, 256, 0, stream>>>(x, Wr, xb, topi, gatesb, cnt_part, f_part, P_part);
  k_reduce<<<1, 256, 0, stream>>>(cnt_part, f_part, P_part, counts, goff, cursor,
                                  tokofp, out + (size_t)NT * DD);
  k_build<<<NT / 256, 256, 0, stream>>>(topi, cursor, tokofp, pos);
  // FC1: 256x256 tile, 512 thr, XCD-chunked (nwg = 8*144 = 1152)
  k_gemm<256, 256, 512, DD, FF, FF / 256, MT256, true>
      <<<dim3(FF / 256, MT256), 512, 0, stream>>>(xb, W1T, b1, h, goff, tokofp);
  // FC2: 256x256 tile, 512 thr, XCD-chunked (nwg = 2*144 = 288)
  k_gemm<256, 256, 512, FF, DD, DD / 256, MT256, false>
      <<<dim3(DD / 256, MT256), 512, 0, stream>>>(h, W2T, b2, ybuf, goff, tokofp);
  k_comb<<<NT, 256, 0, stream>>>(ybuf, pos, gatesb, out);
}